// Round 17
// baseline (63.831 us; speedup 1.0000x reference)
//
#include <hip/hip_runtime.h>
#include <cstddef>

#define BATCH 512
#define UNITS 512
#define HID   64

typedef __bf16 bf16x8 __attribute__((ext_vector_type(8)));
typedef __bf16 bf16x4 __attribute__((ext_vector_type(4)));
typedef float  f32x4  __attribute__((ext_vector_type(4)));

// single v_rcp_f32 (~1ulp) instead of IEEE div sequence; negligible vs bf16 error
__device__ __forceinline__ float fast_sigmoid(float v) {
    return __builtin_amdgcn_rcpf(1.0f + __expf(-v));
}
__device__ __forceinline__ float fast_tanh(float v) {
    return 2.0f * __builtin_amdgcn_rcpf(1.0f + __expf(-2.0f * v)) - 1.0f;
}

// R17 = R15 (sigma-trick, 49.2KB LDS) reshaped to 1024-THREAD BLOCKS.
// Mechanism: R13/R15 use only 60 unified regs/wave -> 8 waves/SIMD are
// register-feasible (512/60), but 512-thread blocks x 2 resident = only 4
// waves/SIMD static. A 1024-thr block (16 waves) x 2 blocks/CU = 8 waves/SIMD
// = 100% static occupancy, with NO extra W traffic (still 1 block per unit).
// Residency needs LDS <= 80KB -> sigma version's 49.2KB (hlds would be 36KB
// at 16 waves and break it). Block placement is all-or-nothing: if regalloc
// lands > 64 total, only 1 block fits -> degrade to ~R15 (acceptable risk).
// R16 lesson: CHUNKS=2 pays +23MB W re-stage and occupancy fell -- dead end.
// Keeps: XCD swizzle (R11 +8%), transposed-D f32x4 stores (R13), depth-1
// prefetch (R13), sigma lane-local h (R15), linear wlds (0 conflicts).
__global__ __launch_bounds__(1024, 2)
void gru_kernel(const float* __restrict__ x,    const float* __restrict__ h,
                const float* __restrict__ W_ir, const float* __restrict__ b_ir,
                const float* __restrict__ W_hr, const float* __restrict__ b_hr,
                const float* __restrict__ W_iz, const float* __restrict__ b_iz,
                const float* __restrict__ W_hz, const float* __restrict__ b_hz,
                const float* __restrict__ W_in, const float* __restrict__ b_in,
                const float* __restrict__ W_hn, const float* __restrict__ b_hn,
                float* __restrict__ out)
{
    __shared__ __align__(16) unsigned char wlds[6 * 512 * 16]; // 48 KB
    __shared__ float blds[4][64];                              // 1 KB

    // XCD swizzle (R11-verified): each XCD gets 64 contiguous units
    const int u    = (blockIdx.x & 7) * 64 + (blockIdx.x >> 3);
    const int tid  = threadIdx.x;
    const int lane = tid & 63;
    const int w    = tid >> 6;   // 0..15 : 16-row group within 256-row tile
    const int lr   = lane & 15;  // A-row / D-row (batch row) within fragment
    const int lg   = lane >> 4;  // k-group 0..3

    // per-wave row base for iter 0; advance by 256 rows per iter (2 iters)
    const float* pxB = x + ((size_t)(w * 16 + lr) * UNITS + u) * HID;
    const float* phB = h + ((size_t)(w * 16 + lr) * UNITS + u) * HID;
    const size_t istep = (size_t)256 * UNITS * HID;
    // sigma offsets: ks=0 half reads cols lg*4 and 16+lg*4; ks=1 adds 32
    const int k0a = lg * 4;
    const int k0b = 16 + lg * 4;

    // ---- iter-0 raw prefetch (issued before staging; hides under it) ----
    f32x4 rx0, rx1, rx2, rx3, rh0, rh1, rh2, rh3;
    rx0 = *(const f32x4*)(pxB + k0a);
    rx1 = *(const f32x4*)(pxB + k0b);
    rx2 = *(const f32x4*)(pxB + 32 + k0a);
    rx3 = *(const f32x4*)(pxB + 32 + k0b);
    rh0 = *(const f32x4*)(phB + k0a);
    rh1 = *(const f32x4*)(phB + k0b);
    rh2 = *(const f32x4*)(phB + 32 + k0a);
    rh3 = *(const f32x4*)(phB + 32 + k0b);

    const float* Wg[6] = {
        W_ir + (size_t)u * 64 * 64, W_hr + (size_t)u * 64 * 64,
        W_iz + (size_t)u * 64 * 64, W_hz + (size_t)u * 64 * 64,
        W_in + (size_t)u * 64 * 64, W_hn + (size_t)u * 64 * 64 };

    // ---- stage weights: 3 passes x 1024 threads, linear LDS, sigma rows ----
    // cid = p*1024 + tid in [0,3072): g = cid>>9 (per-pass compile-time select),
    // c = cid&511: ks=c>>8, n=(c>>6)&3, lg_s=(c>>4)&3, lr_s=c&15.
    // chunk elem e holds W[ks*32 + sigma(lg_s,e)][n*16+lr_s]:
    //   e<4: row = ks*32 + lg_s*4 + e ; e>=4: row = ks*32 + 16 + lg_s*4 + (e-4)
    {
      const int c    = tid & 511;
      const int ks_s = c >> 8;
      const int lg_s = (c >> 4) & 3;
      const int o_s  = (c >> 6 & 3) * 16 + (c & 15);
      #pragma unroll
      for (int p = 0; p < 3; ++p) {
        const float* qb = (tid & 512) ? Wg[p * 2 + 1] : Wg[p * 2];
        const float* q1 = qb + (size_t)(ks_s * 32 + lg_s * 4) * 64 + o_s;
        const float* q2 = q1 + (size_t)16 * 64;
        bf16x8 f;
        #pragma unroll
        for (int e = 0; e < 4; ++e) {
          f[e]     = (__bf16)q1[(size_t)e * 64];
          f[4 + e] = (__bf16)q2[(size_t)e * 64];
        }
        const int cid = p * 1024 + tid;
        *(bf16x8*)(wlds + (size_t)cid * 16) = f;
      }
    }

    // ---- stage bias sums into LDS (1KB) ----
    if (tid < 256) {
      const int o_l = tid & 63;
      const int which = tid >> 6;
      const int o = u * 64 + o_l;
      float v;
      if      (which == 0) v = b_ir[o] + b_hr[o];
      else if (which == 1) v = b_iz[o] + b_hz[o];
      else if (which == 2) v = b_in[o];
      else                 v = b_hn[o];
      blds[which][o_l] = v;
    }

    __syncthreads();

    const f32x4 zero4 = { 0.0f, 0.0f, 0.0f, 0.0f };
    const int loff = lane * 16;

    #pragma unroll 1
    for (int it = 0; it < 2; ++it) {
      const int brow0 = it * 256 + w * 16;

      // ---- pack A fragments (sigma order: elems 0-3 = lo quad, 4-7 = hi) ----
      bf16x8 ax[2], ah[2];
      {
        bf16x8 f;
        #pragma unroll
        for (int e = 0; e < 4; ++e) { f[e] = (__bf16)rx0[e]; f[4+e] = (__bf16)rx1[e]; }
        ax[0] = f;
        #pragma unroll
        for (int e = 0; e < 4; ++e) { f[e] = (__bf16)rx2[e]; f[4+e] = (__bf16)rx3[e]; }
        ax[1] = f;
        #pragma unroll
        for (int e = 0; e < 4; ++e) { f[e] = (__bf16)rh0[e]; f[4+e] = (__bf16)rh1[e]; }
        ah[0] = f;
        #pragma unroll
        for (int e = 0; e < 4; ++e) { f[e] = (__bf16)rh2[e]; f[4+e] = (__bf16)rh3[e]; }
        ah[1] = f;
      }

      // ---- issue next iter's raw loads; latency hides under 48 MFMAs ----
      if (it < 1) {
        const float* px = pxB + istep;
        const float* ph = phB + istep;
        rx0 = *(const f32x4*)(px + k0a);
        rx1 = *(const f32x4*)(px + k0b);
        rx2 = *(const f32x4*)(px + 32 + k0a);
        rx3 = *(const f32x4*)(px + 32 + k0b);
        rh0 = *(const f32x4*)(ph + k0a);
        rh1 = *(const f32x4*)(ph + k0b);
        rh2 = *(const f32x4*)(ph + 32 + k0a);
        rh3 = *(const f32x4*)(ph + 32 + k0b);
      }

      // pin the prefetch loads before the compute section
      __builtin_amdgcn_sched_barrier(0);

      // ---- n-outer: one 16-col fragment at a time ----
      #pragma unroll 1
      for (int n = 0; n < 4; ++n) {
        const f32x4 brv = *(const f32x4*)(&blds[0][n * 16 + lg * 4]);
        const f32x4 bzv = *(const f32x4*)(&blds[1][n * 16 + lg * 4]);
        const f32x4 biv = *(const f32x4*)(&blds[2][n * 16 + lg * 4]);
        const f32x4 bhv = *(const f32x4*)(&blds[3][n * 16 + lg * 4]);

        // h for blend is lane-local (sigma trick): ah[n>>1], quad n&1.
        // Static element extracts + value selects (rule-#20 safe).
        const bf16x8 hsrc = (n < 2) ? ah[0] : ah[1];
        bf16x4 hlo, hhi;
        #pragma unroll
        for (int e = 0; e < 4; ++e) { hlo[e] = hsrc[e]; hhi[e] = hsrc[4 + e]; }
        const bf16x4 hq = (n & 1) ? hhi : hlo;

        f32x4 accr = zero4, accz = zero4, acca = zero4, accb = zero4;
        #pragma unroll
        for (int ks = 0; ks < 2; ++ks) {
          const unsigned char* bp = wlds + ks * 4096 + n * 1024 + loff;
          bf16x8 b0 = *(const bf16x8*)(bp + 0 * 8192);
          bf16x8 b1 = *(const bf16x8*)(bp + 1 * 8192);
          bf16x8 b2 = *(const bf16x8*)(bp + 2 * 8192);
          bf16x8 b3 = *(const bf16x8*)(bp + 3 * 8192);
          bf16x8 b4 = *(const bf16x8*)(bp + 4 * 8192);
          bf16x8 b5 = *(const bf16x8*)(bp + 5 * 8192);
          // SWAPPED operands -> transposed D (R13-verified)
          accr = __builtin_amdgcn_mfma_f32_16x16x32_bf16(b0, ax[ks], accr, 0, 0, 0);
          accr = __builtin_amdgcn_mfma_f32_16x16x32_bf16(b1, ah[ks], accr, 0, 0, 0);
          accz = __builtin_amdgcn_mfma_f32_16x16x32_bf16(b2, ax[ks], accz, 0, 0, 0);
          accz = __builtin_amdgcn_mfma_f32_16x16x32_bf16(b3, ah[ks], accz, 0, 0, 0);
          acca = __builtin_amdgcn_mfma_f32_16x16x32_bf16(b4, ax[ks], acca, 0, 0, 0);
          accb = __builtin_amdgcn_mfma_f32_16x16x32_bf16(b5, ah[ks], accb, 0, 0, 0);
        }

        // ---- epilogue: lane holds out[row=brow0+lr][o=n*16+lg*4+j], j=0..3
        f32x4 ov;
        #pragma unroll
        for (int j = 0; j < 4; ++j) {
          const float rv = fast_sigmoid(accr[j] + brv[j]);
          const float zv = fast_sigmoid(accz[j] + bzv[j]);
          const float nv = fast_tanh(acca[j] + biv[j] + rv * (accb[j] + bhv[j]));
          ov[j] = (1.0f - zv) * nv + zv * (float)hq[j];
        }
        float* po = out + ((size_t)(brow0 + lr) * UNITS + u) * HID + n * 16 + lg * 4;
        *(f32x4*)po = ov;
      }
    }
}

extern "C" void kernel_launch(void* const* d_in, const int* in_sizes, int n_in,
                              void* d_out, int out_size, void* d_ws, size_t ws_size,
                              hipStream_t stream) {
    const float* x    = (const float*)d_in[0];
    const float* h    = (const float*)d_in[1];
    const float* W_ir = (const float*)d_in[2];
    const float* b_ir = (const float*)d_in[3];
    const float* W_hr = (const float*)d_in[4];
    const float* b_hr = (const float*)d_in[5];
    const float* W_iz = (const float*)d_in[6];
    const float* b_iz = (const float*)d_in[7];
    const float* W_hz = (const float*)d_in[8];
    const float* b_hz = (const float*)d_in[9];
    const float* W_in = (const float*)d_in[10];
    const float* b_in = (const float*)d_in[11];
    const float* W_hn = (const float*)d_in[12];
    const float* b_hn = (const float*)d_in[13];
    float* out = (float*)d_out;

    gru_kernel<<<dim3(UNITS), dim3(1024), 0, stream>>>(
        x, h, W_ir, b_ir, W_hr, b_hr, W_iz, b_iz, W_hz, b_hz,
        W_in, b_in, W_hn, b_hn, out);
}

// Round 18
// 47.619 us; speedup vs baseline: 1.3404x; 1.3404x over previous
//
#include <hip/hip_runtime.h>
#include <cstddef>

#define BATCH 512
#define UNITS 512
#define HID   64

typedef __bf16 bf16x8 __attribute__((ext_vector_type(8)));
typedef __bf16 bf16x4 __attribute__((ext_vector_type(4)));
typedef float  f32x4  __attribute__((ext_vector_type(4)));

// single v_rcp_f32 (~1ulp) instead of IEEE div sequence; negligible vs bf16 error
__device__ __forceinline__ float fast_sigmoid(float v) {
    return __builtin_amdgcn_rcpf(1.0f + __expf(-v));
}
__device__ __forceinline__ float fast_tanh(float v) {
    return 2.0f * __builtin_amdgcn_rcpf(1.0f + __expf(-2.0f * v)) - 1.0f;
}

// R18 = R13 (47.5us best) + T5 s_setprio around the MFMA cluster.
// Regime justification: R13's main loop has NO barriers -- 16 resident
// waves/CU free-run at different phases (prefetch-issuing vs MFMA-entering),
// the role-diversity regime where setprio paid on attn (+4-7%, m191), unlike
// lockstep-GEMM (m190 null). Everything else is R13 unchanged.
// Settled lessons: grid hard-capped 2 blocks/CU (CHUNKS re-stage W: net-neg
// x3); regs >64/wave trade 1:1 vs waves (R14/R17); hlds off critical path
// (R15); traffic near-minimal (FETCH 92MB h-single-read, WRITE 66MB).
__global__ __launch_bounds__(512, 2)
void gru_kernel(const float* __restrict__ x,    const float* __restrict__ h,
                const float* __restrict__ W_ir, const float* __restrict__ b_ir,
                const float* __restrict__ W_hr, const float* __restrict__ b_hr,
                const float* __restrict__ W_iz, const float* __restrict__ b_iz,
                const float* __restrict__ W_hz, const float* __restrict__ b_hz,
                const float* __restrict__ W_in, const float* __restrict__ b_in,
                const float* __restrict__ W_hn, const float* __restrict__ b_hn,
                float* __restrict__ out)
{
    __shared__ __align__(16) unsigned char wlds[6 * 512 * 16]; // 48 KB
    __shared__ float blds[4][64];                              // 1 KB
    __shared__ __align__(16) __bf16 hlds[8][16][72];           // 18 KB (72 = 64 + 8 pad)

    // XCD swizzle (R11-verified: -8%): each XCD gets 64 contiguous units
    const int u    = (blockIdx.x & 7) * 64 + (blockIdx.x >> 3);
    const int tid  = threadIdx.x;
    const int lane = tid & 63;
    const int w    = tid >> 6;   // 0..7 : 16-row group within 128-row tile
    const int lr   = lane & 15;  // A-row / D-row (batch row) within fragment
    const int lg   = lane >> 4;  // k-group 0..3

    // per-wave row base for iter 0; advance by 128 rows per iter
    const float* pxB = x + ((size_t)(w * 16 + lr) * UNITS + u) * HID;
    const float* phB = h + ((size_t)(w * 16 + lr) * UNITS + u) * HID;
    const size_t istep = (size_t)128 * UNITS * HID;
    const int k0 = lg * 8;          // ks=0 base
    const int k1 = 32 + lg * 8;     // ks=1 base

    // ---- iter-0 raw prefetch (issued before staging; hides under it) ----
    f32x4 rx0, rx1, rx2, rx3, rh0, rh1, rh2, rh3;
    rx0 = *(const f32x4*)(pxB + k0);
    rx1 = *(const f32x4*)(pxB + k0 + 4);
    rx2 = *(const f32x4*)(pxB + k1);
    rx3 = *(const f32x4*)(pxB + k1 + 4);
    rh0 = *(const f32x4*)(phB + k0);
    rh1 = *(const f32x4*)(phB + k0 + 4);
    rh2 = *(const f32x4*)(phB + k1);
    rh3 = *(const f32x4*)(phB + k1 + 4);

    const float* Wg[6] = {
        W_ir + (size_t)u * 64 * 64, W_hr + (size_t)u * 64 * 64,
        W_iz + (size_t)u * 64 * 64, W_hz + (size_t)u * 64 * 64,
        W_in + (size_t)u * 64 * 64, W_hn + (size_t)u * 64 * 64 };

    // ---- stage weights: 6 passes, linear LDS writes (R8-verified) ----
    {
      const int ks_s = tid >> 8;
      const int n_s  = (tid >> 6) & 3;
      const int lg_s = (tid >> 4) & 3;
      const int lr_s = tid & 15;
      const int i0   = ks_s * 32 + lg_s * 8;
      const int o_s  = n_s * 16 + lr_s;
      #pragma unroll
      for (int g = 0; g < 6; ++g) {
        const float* q = Wg[g] + (size_t)i0 * 64 + o_s;
        bf16x8 f;
        #pragma unroll
        for (int e = 0; e < 8; ++e) f[e] = (__bf16)q[(size_t)e * 64];
        *(bf16x8*)(wlds + (size_t)(g * 512 + tid) * 16) = f;
      }
    }

    // ---- stage bias sums into LDS (1KB) ----
    if (tid < 256) {
      const int o_l = tid & 63;
      const int which = tid >> 6;
      const int o = u * 64 + o_l;
      float v;
      if      (which == 0) v = b_ir[o] + b_hr[o];
      else if (which == 1) v = b_iz[o] + b_hz[o];
      else if (which == 2) v = b_in[o];
      else                 v = b_hn[o];
      blds[which][o_l] = v;
    }

    __syncthreads();

    const f32x4 zero4 = { 0.0f, 0.0f, 0.0f, 0.0f };
    const int loff = lane * 16;

    #pragma unroll 1
    for (int it = 0; it < 4; ++it) {
      const int brow0 = it * 128 + w * 16;

      // ---- pack A fragments from the prefetched raw values ----
      bf16x8 ax[2], ah[2];
      {
        bf16x8 f;
        #pragma unroll
        for (int e = 0; e < 4; ++e) { f[e] = (__bf16)rx0[e]; f[4+e] = (__bf16)rx1[e]; }
        ax[0] = f;
        #pragma unroll
        for (int e = 0; e < 4; ++e) { f[e] = (__bf16)rx2[e]; f[4+e] = (__bf16)rx3[e]; }
        ax[1] = f;
        #pragma unroll
        for (int e = 0; e < 4; ++e) { f[e] = (__bf16)rh0[e]; f[4+e] = (__bf16)rh1[e]; }
        ah[0] = f;
        #pragma unroll
        for (int e = 0; e < 4; ++e) { f[e] = (__bf16)rh2[e]; f[4+e] = (__bf16)rh3[e]; }
        ah[1] = f;
      }

      // ---- issue next iter's raw loads (overwrite rx/rh after pack) ----
      if (it < 3) {
        const float* px = pxB + (size_t)(it + 1) * istep;
        const float* ph = phB + (size_t)(it + 1) * istep;
        rx0 = *(const f32x4*)(px + k0);
        rx1 = *(const f32x4*)(px + k0 + 4);
        rx2 = *(const f32x4*)(px + k1);
        rx3 = *(const f32x4*)(px + k1 + 4);
        rh0 = *(const f32x4*)(ph + k0);
        rh1 = *(const f32x4*)(ph + k0 + 4);
        rh2 = *(const f32x4*)(ph + k1);
        rh3 = *(const f32x4*)(ph + k1 + 4);
      }

      // ---- stash this iter's h tile (bf16) in wave-private LDS ----
      *(bf16x8*)(&hlds[w][lr][lg * 8])      = ah[0];
      *(bf16x8*)(&hlds[w][lr][32 + lg * 8]) = ah[1];

      // pin the prefetch loads + ds_writes before the compute section
      __builtin_amdgcn_sched_barrier(0);

      // ---- n-outer: one 16-col fragment at a time ----
      #pragma unroll 1
      for (int n = 0; n < 4; ++n) {
        const f32x4 brv = *(const f32x4*)(&blds[0][n * 16 + lg * 4]);
        const f32x4 bzv = *(const f32x4*)(&blds[1][n * 16 + lg * 4]);
        const f32x4 biv = *(const f32x4*)(&blds[2][n * 16 + lg * 4]);
        const f32x4 bhv = *(const f32x4*)(&blds[3][n * 16 + lg * 4]);
        const bf16x4 hq = *(const bf16x4*)(&hlds[w][lr][n * 16 + lg * 4]);

        f32x4 accr = zero4, accz = zero4, acca = zero4, accb = zero4;
        // T5: bias the CU scheduler toward this wave while it feeds the
        // matrix pipe (waves are barrier-free and phase-diverse here)
        __builtin_amdgcn_s_setprio(1);
        #pragma unroll
        for (int ks = 0; ks < 2; ++ks) {
          const unsigned char* bp = wlds + ks * 4096 + n * 1024 + loff;
          bf16x8 b0 = *(const bf16x8*)(bp + 0 * 8192);
          bf16x8 b1 = *(const bf16x8*)(bp + 1 * 8192);
          bf16x8 b2 = *(const bf16x8*)(bp + 2 * 8192);
          bf16x8 b3 = *(const bf16x8*)(bp + 3 * 8192);
          bf16x8 b4 = *(const bf16x8*)(bp + 4 * 8192);
          bf16x8 b5 = *(const bf16x8*)(bp + 5 * 8192);
          // SWAPPED operands -> transposed D (R13-verified)
          accr = __builtin_amdgcn_mfma_f32_16x16x32_bf16(b0, ax[ks], accr, 0, 0, 0);
          accr = __builtin_amdgcn_mfma_f32_16x16x32_bf16(b1, ah[ks], accr, 0, 0, 0);
          accz = __builtin_amdgcn_mfma_f32_16x16x32_bf16(b2, ax[ks], accz, 0, 0, 0);
          accz = __builtin_amdgcn_mfma_f32_16x16x32_bf16(b3, ah[ks], accz, 0, 0, 0);
          acca = __builtin_amdgcn_mfma_f32_16x16x32_bf16(b4, ax[ks], acca, 0, 0, 0);
          accb = __builtin_amdgcn_mfma_f32_16x16x32_bf16(b5, ah[ks], accb, 0, 0, 0);
        }
        __builtin_amdgcn_s_setprio(0);

        // epilogue: lane holds out[row=brow0+lr][o=n*16+lg*4+j], j=0..3
        f32x4 ov;
        #pragma unroll
        for (int j = 0; j < 4; ++j) {
          const float rv = fast_sigmoid(accr[j] + brv[j]);
          const float zv = fast_sigmoid(accz[j] + bzv[j]);
          const float nv = fast_tanh(acca[j] + biv[j] + rv * (accb[j] + bhv[j]));
          ov[j] = (1.0f - zv) * nv + zv * (float)hq[j];
        }
        float* po = out + ((size_t)(brow0 + lr) * UNITS + u) * HID + n * 16 + lg * 4;
        *(f32x4*)po = ov;
      }
    }
}

extern "C" void kernel_launch(void* const* d_in, const int* in_sizes, int n_in,
                              void* d_out, int out_size, void* d_ws, size_t ws_size,
                              hipStream_t stream) {
    const float* x    = (const float*)d_in[0];
    const float* h    = (const float*)d_in[1];
    const float* W_ir = (const float*)d_in[2];
    const float* b_ir = (const float*)d_in[3];
    const float* W_hr = (const float*)d_in[4];
    const float* b_hr = (const float*)d_in[5];
    const float* W_iz = (const float*)d_in[6];
    const float* b_iz = (const float*)d_in[7];
    const float* W_hz = (const float*)d_in[8];
    const float* b_hz = (const float*)d_in[9];
    const float* W_in = (const float*)d_in[10];
    const float* b_in = (const float*)d_in[11];
    const float* W_hn = (const float*)d_in[12];
    const float* b_hn = (const float*)d_in[13];
    float* out = (float*)d_out;

    gru_kernel<<<dim3(UNITS), dim3(512), 0, stream>>>(
        x, h, W_ir, b_ir, W_hr, b_hr, W_iz, b_iz, W_hz, b_hz,
        W_in, b_in, W_hn, b_hn, out);
}